// Round 3
// baseline (444.844 us; speedup 1.0000x reference)
//
#include <hip/hip_runtime.h>
#include <math.h>

#define ROW_N 2048
#define KSEL 10
#define WCAP 64   // per-wave candidate cap

typedef float f32x4 __attribute__((ext_vector_type(4)));

// Wave-per-row: each 64-lane wave owns one row of 2048 f32 (32 elems/lane,
// 8 x float4 at stride 256). A 256-thread block = 4 independent rows and
// contains ZERO __syncthreads -- all reductions are shfl_xor butterflies,
// candidate compaction is ballot+mbcnt into a wave-private LDS slice
// (in-wave LDS write->read needs no barrier: LDS pipe is in-order per wave).
//
// Selection: threshold T = mu + 2.2*sigma (count ~Binomial(2048,0.0139),
// mean ~29, P(<10) ~1e-3 -> cheap wave-local retry; P(>64) ~1e-11 -> raise).
// Exact top-10 boundary key kmin found by 48-bit ballot binary search over
// packed keys (ord_val<<16 | (2047-idx)) -- exact lax.top_k tie-break, no
// LDS-pipe rank loop. Every element then computes its final value directly:
//   key >= kmin ? 0.9*exp(v-vmax)/ssum : 0.1*exp(v-shift)/rem
// so there is no scatter/patch pass and no store-ordering barrier.
__global__ __launch_bounds__(256) void topk_softmax_kernel(
    const float* __restrict__ in, float* __restrict__ out)
{
    const int tid  = threadIdx.x;
    const int lane = tid & 63;
    const int wave = tid >> 6;
    const size_t base = ((size_t)blockIdx.x * 4 + wave) * ROW_N;

    __shared__ unsigned long long s_cand[4][WCAP];   // 2 KB, wave-private slices

    const f32x4* p4 = reinterpret_cast<const f32x4*>(in + base);
    f32x4 v4[8];
    #pragma unroll
    for (int j = 0; j < 8; ++j) v4[j] = p4[j * 64 + lane];

    // fused row stats: sum, sum-of-squares, max (one pass, 3 butterflies)
    float s = 0.f, q = 0.f, vm = -INFINITY;
    #pragma unroll
    for (int j = 0; j < 8; ++j)
        #pragma unroll
        for (int c = 0; c < 4; ++c) {
            float x = v4[j][c];
            s += x; q = fmaf(x, x, q); vm = fmaxf(vm, x);
        }
    #pragma unroll
    for (int off = 32; off > 0; off >>= 1) {
        s += __shfl_xor(s, off);
        q += __shfl_xor(q, off);
        vm = fmaxf(vm, __shfl_xor(vm, off));
    }
    const float mu    = s * (1.f / ROW_N);
    const float sig   = sqrtf(fmaxf(q * (1.f / ROW_N) - mu * mu, 1e-20f));
    const float shift = fmaf(4.f, sig, mu);   // shared exp frame for remaining mass
    const float vmax  = vm;                   // exact row max (= top-1 value)
    float Tf = fmaf(2.2f, sig, mu);           // candidate threshold

    // total exp mass in shift frame (rem = total - top10 mass; no mask needed)
    float tot = 0.f;
    #pragma unroll
    for (int j = 0; j < 8; ++j)
        #pragma unroll
        for (int c = 0; c < 4; ++c)
            tot += __expf(v4[j][c] - shift);
    #pragma unroll
    for (int off = 32; off > 0; off >>= 1) tot += __shfl_xor(tot, off);

    // ballot+mbcnt compaction of candidates (v > T) into wave slice; count is
    // uniform from popcounts -- no LDS counter, no atomics.
    auto collect = [&](float T) -> int {
        int cnt = 0;
        #pragma unroll
        for (int j = 0; j < 8; ++j)
            #pragma unroll
            for (int c = 0; c < 4; ++c) {
                bool cond = v4[j][c] > T;
                unsigned long long m = __ballot(cond);
                if (cond) {
                    int idx = j * 256 + lane * 4 + c;
                    uint32_t u  = __float_as_uint(v4[j][c]);
                    uint32_t ov = u ^ ((uint32_t)((int32_t)u >> 31) | 0x80000000u);
                    int pos = cnt + (int)__builtin_amdgcn_mbcnt_hi(
                                        (unsigned)(m >> 32),
                                        __builtin_amdgcn_mbcnt_lo((unsigned)m, 0u));
                    if (pos < WCAP)
                        s_cand[wave][pos] = ((unsigned long long)ov << 16) |
                                            (unsigned)(2047 - idx);
                }
                cnt += __popcll(m);
            }
        return cnt;
    };

    int C = collect(Tf);
    int tries = 0;
    while ((C < KSEL || C > WCAP) && tries < 8) {   // wave-uniform, rare
        Tf += (C < KSEL) ? (-0.5f * sig) : (0.5f * sig);
        C = collect(Tf);
        ++tries;
    }
    if (C > WCAP) C = WCAP;

    // one candidate key per lane (in-wave LDS, no barrier needed)
    unsigned long long k0 = (lane < C) ? s_cand[wave][lane] : 0ULL;

    // 48-bit ballot binary search: largest T with |{key >= T}| >= 10 is
    // exactly the 10th-largest key (keys unique). Mostly SALU, no LDS pipe.
    unsigned long long kmin = 0ULL;
    #pragma unroll
    for (int b = 47; b >= 0; --b) {
        unsigned long long trial = kmin | (1ULL << b);
        unsigned long long m = __ballot(k0 >= trial);
        if (__popcll(m) >= KSEL) kmin = trial;
    }

    // top-10 softmax mass (exactly the 10 lanes with k0 >= kmin; k0=0 lanes
    // are excluded since kmin > 0 for any valid row)
    uint32_t ovk = (uint32_t)(k0 >> 16);
    float val = __uint_as_float(ovk ^ ((ovk & 0x80000000u) ? 0x80000000u
                                                          : 0xFFFFFFFFu));
    float ee = (k0 >= kmin) ? __expf(val - vmax) : 0.f;
    float ssum = ee;
    #pragma unroll
    for (int off = 32; off > 0; off >>= 1) ssum += __shfl_xor(ssum, off);

    const float tsum = ssum * __expf(vmax - shift);  // top-10 mass in shift frame
    const float rem  = tot - tsum;
    const float aa   = 0.9f / ssum;   // top-k scale   (frame: vmax)
    const float bb   = 0.1f / rem;    // remaining scale (frame: shift)

    // branch-free final write: per-element select of (frame, scale)
    f32x4* o4 = reinterpret_cast<f32x4*>(out + base);
    #pragma unroll
    for (int j = 0; j < 8; ++j) {
        f32x4 o;
        #pragma unroll
        for (int c = 0; c < 4; ++c) {
            float x = v4[j][c];
            int idx = j * 256 + lane * 4 + c;
            uint32_t u  = __float_as_uint(x);
            uint32_t ov = u ^ ((uint32_t)((int32_t)u >> 31) | 0x80000000u);
            unsigned long long key = ((unsigned long long)ov << 16) |
                                     (unsigned)(2047 - idx);
            bool sel = key >= kmin;
            o[c] = __expf(x - (sel ? vmax : shift)) * (sel ? aa : bb);
        }
        __builtin_nontemporal_store(o, o4 + j * 64 + lane);
    }
}

extern "C" void kernel_launch(void* const* d_in, const int* in_sizes, int n_in,
                              void* d_out, int out_size, void* d_ws, size_t ws_size,
                              hipStream_t stream) {
    const float* logits = (const float*)d_in[0];
    float* out = (float*)d_out;
    const int rows = out_size / ROW_N;          // 2*8*2048 = 32768
    topk_softmax_kernel<<<dim3(rows / 4), dim3(256), 0, stream>>>(logits, out);
}